// Round 6
// baseline (250.020 us; speedup 1.0000x reference)
//
#include <hip/hip_runtime.h>

// Integrate-and-fire SNN forward (IF_88957362634870).
// x: 8 frames of N = 4,194,304 fp32 (16 MiB each); out: 8 frames.
// R0-R5 finding: every single-kernel variant (VGPR 20-36, G=1/2, NT stores,
// asm-forced 8-load bursts) hits a ~2.1-2.35 TB/s wall -> NOT wave-level
// MLP-bound. Theory: 8 read + 8 write streams (2^24-strided) with
// fine-grained read/write interleave kills DRAM/fabric efficiency ~3x vs
// the 1R+1W copy pattern that reaches 6.3 TB/s.
// R6 experiment: split into read-dominant (phases 1+2 -> sc into ws) and
// write-dominant (phase 3: sc -> 8 NT output frames) dispatches. sc is
// 16 MiB, produced and consumed by the same block index -> same XCD -> L2.

#define T1 8
#define T2 8
#define L_DIV 8.0f
#define EPS_C (-8e-05f)

typedef float fvec4 __attribute__((ext_vector_type(4)));

// ---------------- Kernel A: phases 1+2, x -> sc ----------------
__global__ __launch_bounds__(256) void if_phase12_kernel(
    const fvec4* __restrict__ x,
    const float* __restrict__ thresh,
    fvec4* __restrict__ sc_out,
    int n4)
{
    const int i = blockIdx.x * blockDim.x + threadIdx.x;
    const float thre = thresh[0] / L_DIV;

    const fvec4* a0 = &x[(size_t)0 * n4 + i];
    const fvec4* a1 = &x[(size_t)1 * n4 + i];
    const fvec4* a2 = &x[(size_t)2 * n4 + i];
    const fvec4* a3 = &x[(size_t)3 * n4 + i];
    const fvec4* a4 = &x[(size_t)4 * n4 + i];
    const fvec4* a5 = &x[(size_t)5 * n4 + i];
    const fvec4* a6 = &x[(size_t)6 * n4 + i];
    const fvec4* a7 = &x[(size_t)7 * n4 + i];

    fvec4 xv[T1];
    asm volatile(
        "global_load_dwordx4 %0, %8, off\n\t"
        "global_load_dwordx4 %1, %9, off\n\t"
        "global_load_dwordx4 %2, %10, off\n\t"
        "global_load_dwordx4 %3, %11, off\n\t"
        "global_load_dwordx4 %4, %12, off\n\t"
        "global_load_dwordx4 %5, %13, off\n\t"
        "global_load_dwordx4 %6, %14, off\n\t"
        "global_load_dwordx4 %7, %15, off\n\t"
        "s_waitcnt vmcnt(0)"
        : "=&v"(xv[0]), "=&v"(xv[1]), "=&v"(xv[2]), "=&v"(xv[3]),
          "=&v"(xv[4]), "=&v"(xv[5]), "=&v"(xv[6]), "=&v"(xv[7])
        : "v"(a0), "v"(a1), "v"(a2), "v"(a3),
          "v"(a4), "v"(a5), "v"(a6), "v"(a7)
        : "memory");

    float m[4], sc[4];
    #pragma unroll
    for (int k = 0; k < 4; ++k) { m[k] = 0.5f * thre; sc[k] = 0.0f; }

    // Phase 1: integrate T1 frames, fire-and-subtract.
    #pragma unroll
    for (int t = 0; t < T1; ++t) {
        #pragma unroll
        for (int k = 0; k < 4; ++k) {
            m[k] += xv[t][k];
            const float spike = (m[k] - thre >= EPS_C) ? thre : 0.0f;
            m[k] -= spike;
            sc[k] += spike;
        }
    }

    // Phase 2: 7 relaxation steps with reverse spikes.
    #pragma unroll
    for (int t = 0; t < T1 - 1; ++t) {
        #pragma unroll
        for (int k = 0; k < 4; ++k) {
            const float spike = (m[k] - thre >= EPS_C) ? thre : 0.0f;
            const float rev   = (-m[k] > 0.0f) ? thre : 0.0f;
            m[k] = m[k] - spike + rev;
            sc[k] += spike - rev;
        }
    }

    fvec4 o;
    #pragma unroll
    for (int k = 0; k < 4; ++k) o[k] = sc[k];
    sc_out[i] = o;   // regular store: keep sc in L2/L3 for kernel B
}

// ---------------- Kernel B: phase 3, sc -> out ----------------
__global__ __launch_bounds__(256) void if_phase3_kernel(
    const fvec4* __restrict__ sc_in,
    const float* __restrict__ thresh,
    fvec4* __restrict__ out,
    int n4)
{
    const int i = blockIdx.x * blockDim.x + threadIdx.x;
    const float thre = thresh[0] / L_DIV;

    const fvec4 scv = sc_in[i];
    float sc[4] = {scv[0], scv[1], scv[2], scv[3]};

    #pragma unroll
    for (int t = 0; t < T2; ++t) {
        fvec4 o;
        #pragma unroll
        for (int k = 0; k < 4; ++k) {
            const float spike = (sc[k] - thre >= EPS_C) ? thre : 0.0f;
            o[k] = spike;
            sc[k] -= spike;
        }
        __builtin_nontemporal_store(o, &out[(size_t)t * n4 + i]);
    }
}

// ---------------- Fallback: fused (R4, best single-kernel) ----------------
#define G 2
__global__ __launch_bounds__(256) void if_fused_kernel(
    const fvec4* __restrict__ x,
    const float* __restrict__ thresh,
    fvec4* __restrict__ out,
    int n4)
{
    const int base = blockIdx.x * (blockDim.x * G) + threadIdx.x;
    const float thre = thresh[0] / L_DIV;

    fvec4 xv[G][T1];
    #pragma unroll
    for (int t = 0; t < T1; ++t)
        #pragma unroll
        for (int g = 0; g < G; ++g)
            xv[g][t] = x[(size_t)t * n4 + base + g * 256];

    float m[G][4], sc[G][4];
    #pragma unroll
    for (int g = 0; g < G; ++g)
        #pragma unroll
        for (int k = 0; k < 4; ++k) { m[g][k] = 0.5f * thre; sc[g][k] = 0.0f; }

    #pragma unroll
    for (int t = 0; t < T1; ++t)
        #pragma unroll
        for (int g = 0; g < G; ++g)
            #pragma unroll
            for (int k = 0; k < 4; ++k) {
                m[g][k] += xv[g][t][k];
                const float spike = (m[g][k] - thre >= EPS_C) ? thre : 0.0f;
                m[g][k] -= spike;
                sc[g][k] += spike;
            }

    #pragma unroll
    for (int t = 0; t < T1 - 1; ++t)
        #pragma unroll
        for (int g = 0; g < G; ++g)
            #pragma unroll
            for (int k = 0; k < 4; ++k) {
                const float spike = (m[g][k] - thre >= EPS_C) ? thre : 0.0f;
                const float rev   = (-m[g][k] > 0.0f) ? thre : 0.0f;
                m[g][k] = m[g][k] - spike + rev;
                sc[g][k] += spike - rev;
            }

    #pragma unroll
    for (int t = 0; t < T2; ++t)
        #pragma unroll
        for (int g = 0; g < G; ++g) {
            fvec4 o;
            #pragma unroll
            for (int k = 0; k < 4; ++k) {
                const float spike = (sc[g][k] - thre >= EPS_C) ? thre : 0.0f;
                o[k] = spike;
                sc[g][k] -= spike;
            }
            __builtin_nontemporal_store(o, &out[(size_t)t * n4 + base + g * 256]);
        }
}

extern "C" void kernel_launch(void* const* d_in, const int* in_sizes, int n_in,
                              void* d_out, int out_size, void* d_ws, size_t ws_size,
                              hipStream_t stream) {
    const fvec4* x      = (const fvec4*)d_in[0];
    const float* thresh = (const float*)d_in[1];
    fvec4*       out    = (fvec4*)d_out;

    const int N  = in_sizes[0] / T1;  // 4,194,304
    const int n4 = N / 4;             // 1,048,576
    const int block = 256;

    const size_t sc_bytes = (size_t)N * sizeof(float);  // 16 MiB

    if (ws_size >= sc_bytes) {
        fvec4* sc = (fvec4*)d_ws;
        const int grid = n4 / block;  // 4096
        if_phase12_kernel<<<grid, block, 0, stream>>>(x, thresh, sc, n4);
        if_phase3_kernel<<<grid, block, 0, stream>>>(sc, thresh, out, n4);
    } else {
        const int grid = n4 / (block * G);  // 2048
        if_fused_kernel<<<grid, block, 0, stream>>>(x, thresh, out, n4);
    }
}

// Round 7
// 243.505 us; speedup vs baseline: 1.0268x; 1.0268x over previous
//
#include <hip/hip_runtime.h>

// Integrate-and-fire SNN forward (IF_88957362634870).
// x: 8 frames of N = 4,194,304 fp32 (16 MiB each); out: 8 frames.
//
// Evidence so far: every structure with 8 concurrent 2^24-strided streams
// per block sticks at 2.1-2.35 TB/s, while the harness's contiguous
// 512 MB fill runs at 6.5 TB/s on the same device. R7 experiment: give the
// write side a fill-shaped pattern. Phase 3 closed form:
//   out[t][i] = thre * [ sc[i] - (t+1)*thre >= EPS ]
// (fires are a prefix in t; exact at thre=0.125 since sc is an exact
// multiple of 0.125) -> one block per (frame t, span s): 1 contiguous read
// stream + 1 contiguous NT write stream.

#define T1 8
#define T2 8
#define L_DIV 8.0f
#define EPS_C (-8e-05f)

typedef float fvec4 __attribute__((ext_vector_type(4)));

// ---------------- Kernel A: phases 1+2, x -> sc (unchanged from R6) --------
__global__ __launch_bounds__(256) void if_phase12_kernel(
    const fvec4* __restrict__ x,
    const float* __restrict__ thresh,
    fvec4* __restrict__ sc_out,
    int n4)
{
    const int i = blockIdx.x * blockDim.x + threadIdx.x;
    const float thre = thresh[0] / L_DIV;

    const fvec4* a0 = &x[(size_t)0 * n4 + i];
    const fvec4* a1 = &x[(size_t)1 * n4 + i];
    const fvec4* a2 = &x[(size_t)2 * n4 + i];
    const fvec4* a3 = &x[(size_t)3 * n4 + i];
    const fvec4* a4 = &x[(size_t)4 * n4 + i];
    const fvec4* a5 = &x[(size_t)5 * n4 + i];
    const fvec4* a6 = &x[(size_t)6 * n4 + i];
    const fvec4* a7 = &x[(size_t)7 * n4 + i];

    fvec4 xv[T1];
    asm volatile(
        "global_load_dwordx4 %0, %8, off\n\t"
        "global_load_dwordx4 %1, %9, off\n\t"
        "global_load_dwordx4 %2, %10, off\n\t"
        "global_load_dwordx4 %3, %11, off\n\t"
        "global_load_dwordx4 %4, %12, off\n\t"
        "global_load_dwordx4 %5, %13, off\n\t"
        "global_load_dwordx4 %6, %14, off\n\t"
        "global_load_dwordx4 %7, %15, off\n\t"
        "s_waitcnt vmcnt(0)"
        : "=&v"(xv[0]), "=&v"(xv[1]), "=&v"(xv[2]), "=&v"(xv[3]),
          "=&v"(xv[4]), "=&v"(xv[5]), "=&v"(xv[6]), "=&v"(xv[7])
        : "v"(a0), "v"(a1), "v"(a2), "v"(a3),
          "v"(a4), "v"(a5), "v"(a6), "v"(a7)
        : "memory");

    float m[4], sc[4];
    #pragma unroll
    for (int k = 0; k < 4; ++k) { m[k] = 0.5f * thre; sc[k] = 0.0f; }

    #pragma unroll
    for (int t = 0; t < T1; ++t) {
        #pragma unroll
        for (int k = 0; k < 4; ++k) {
            m[k] += xv[t][k];
            const float spike = (m[k] - thre >= EPS_C) ? thre : 0.0f;
            m[k] -= spike;
            sc[k] += spike;
        }
    }

    #pragma unroll
    for (int t = 0; t < T1 - 1; ++t) {
        #pragma unroll
        for (int k = 0; k < 4; ++k) {
            const float spike = (m[k] - thre >= EPS_C) ? thre : 0.0f;
            const float rev   = (-m[k] > 0.0f) ? thre : 0.0f;
            m[k] = m[k] - spike + rev;
            sc[k] += spike - rev;
        }
    }

    fvec4 o;
    #pragma unroll
    for (int k = 0; k < 4; ++k) o[k] = sc[k];
    sc_out[i] = o;   // regular store: keep sc in L2/IF$ for kernel B
}

// ---- Kernel B: phase 3 closed form, one (frame, span) per block ----
// block bid: t = bid >> 10, s = bid & 1023. Block covers 1024 contiguous
// fvec4 groups of frame t: 16 KB contiguous read (IF$-hot) + 16 KB
// contiguous NT write. Fill-shaped: 1 read stream + 1 write stream.
__global__ __launch_bounds__(256) void if_phase3_kernel(
    const fvec4* __restrict__ sc_in,
    const float* __restrict__ thresh,
    fvec4* __restrict__ out,
    int n4)
{
    const int bid = blockIdx.x;
    const int t   = bid >> 10;
    const int s   = bid & 1023;
    const int base = s * 1024 + threadIdx.x;

    const float thre = thresh[0] / L_DIV;
    const float cut  = (float)(t + 1) * thre;   // exact for thre = 2^-3

    fvec4* outt = out + (size_t)t * n4;

    #pragma unroll
    for (int c = 0; c < 4; ++c) {
        const int i = base + c * 256;
        const fvec4 scv = sc_in[i];
        fvec4 o;
        #pragma unroll
        for (int k = 0; k < 4; ++k) {
            o[k] = (scv[k] - cut >= EPS_C) ? thre : 0.0f;
        }
        __builtin_nontemporal_store(o, &outt[i]);
    }
}

// ---------------- Fallback: fused (R4, best single-kernel) ----------------
#define G 2
__global__ __launch_bounds__(256) void if_fused_kernel(
    const fvec4* __restrict__ x,
    const float* __restrict__ thresh,
    fvec4* __restrict__ out,
    int n4)
{
    const int base = blockIdx.x * (blockDim.x * G) + threadIdx.x;
    const float thre = thresh[0] / L_DIV;

    fvec4 xv[G][T1];
    #pragma unroll
    for (int t = 0; t < T1; ++t)
        #pragma unroll
        for (int g = 0; g < G; ++g)
            xv[g][t] = x[(size_t)t * n4 + base + g * 256];

    float m[G][4], sc[G][4];
    #pragma unroll
    for (int g = 0; g < G; ++g)
        #pragma unroll
        for (int k = 0; k < 4; ++k) { m[g][k] = 0.5f * thre; sc[g][k] = 0.0f; }

    #pragma unroll
    for (int t = 0; t < T1; ++t)
        #pragma unroll
        for (int g = 0; g < G; ++g)
            #pragma unroll
            for (int k = 0; k < 4; ++k) {
                m[g][k] += xv[g][t][k];
                const float spike = (m[g][k] - thre >= EPS_C) ? thre : 0.0f;
                m[g][k] -= spike;
                sc[g][k] += spike;
            }

    #pragma unroll
    for (int t = 0; t < T1 - 1; ++t)
        #pragma unroll
        for (int g = 0; g < G; ++g)
            #pragma unroll
            for (int k = 0; k < 4; ++k) {
                const float spike = (m[g][k] - thre >= EPS_C) ? thre : 0.0f;
                const float rev   = (-m[g][k] > 0.0f) ? thre : 0.0f;
                m[g][k] = m[g][k] - spike + rev;
                sc[g][k] += spike - rev;
            }

    #pragma unroll
    for (int t = 0; t < T2; ++t)
        #pragma unroll
        for (int g = 0; g < G; ++g) {
            fvec4 o;
            #pragma unroll
            for (int k = 0; k < 4; ++k) {
                const float spike = (sc[g][k] - thre >= EPS_C) ? thre : 0.0f;
                o[k] = spike;
                sc[g][k] -= spike;
            }
            __builtin_nontemporal_store(o, &out[(size_t)t * n4 + base + g * 256]);
        }
}

extern "C" void kernel_launch(void* const* d_in, const int* in_sizes, int n_in,
                              void* d_out, int out_size, void* d_ws, size_t ws_size,
                              hipStream_t stream) {
    const fvec4* x      = (const fvec4*)d_in[0];
    const float* thresh = (const float*)d_in[1];
    fvec4*       out    = (fvec4*)d_out;

    const int N  = in_sizes[0] / T1;  // 4,194,304
    const int n4 = N / 4;             // 1,048,576
    const int block = 256;

    const size_t sc_bytes = (size_t)N * sizeof(float);  // 16 MiB

    if (ws_size >= sc_bytes) {
        fvec4* sc = (fvec4*)d_ws;
        if_phase12_kernel<<<n4 / block, block, 0, stream>>>(x, thresh, sc, n4);
        // 1024 spans * 8 frames; each block: 1024 groups of one frame.
        if_phase3_kernel<<<(n4 / 1024) * T2, block, 0, stream>>>(sc, thresh, out, n4);
    } else {
        if_fused_kernel<<<n4 / (block * G), block, 0, stream>>>(x, thresh, out, n4);
    }
}